// Round 1
// baseline (1468.717 us; speedup 1.0000x reference)
//
#include <hip/hip_runtime.h>

#define N_NODES 100000
#define N_EDGES 1600000
#define D 64

// K1: out = (1+eps) * feat   (also serves as zero-init replacement for agg)
__global__ void __launch_bounds__(256) init_out_kernel(
    const float* __restrict__ feat, const float* __restrict__ eps,
    float* __restrict__ out) {
  int i = blockIdx.x * blockDim.x + threadIdx.x;  // float4 index, exact grid
  float e = 1.0f + eps[0];
  float4 f = reinterpret_cast<const float4*>(feat)[i];
  float4 o;
  o.x = e * f.x; o.y = e * f.y; o.z = e * f.z; o.w = e * f.w;
  reinterpret_cast<float4*>(out)[i] = o;
}

// K2: for each edge, out[dst] += feat[src]  (16 lanes per edge, float4 each)
__global__ void __launch_bounds__(256) scatter_edges_kernel(
    const float* __restrict__ feat, const int* __restrict__ src,
    const int* __restrict__ dst, float* __restrict__ out) {
  int t = blockIdx.x * blockDim.x + threadIdx.x;
  int e = t >> 4;   // edge id
  int q = t & 15;   // float4 slot within the 64-float row
  int s = src[e];
  int d = dst[e];
  float4 v = reinterpret_cast<const float4*>(feat)[s * 16 + q];
  float* op = out + d * D + q * 4;
  atomicAdd(op + 0, v.x);
  atomicAdd(op + 1, v.y);
  atomicAdd(op + 2, v.z);
  atomicAdd(op + 3, v.w);
}

// K3: in-place row-local GEMM: out[row] = out[row] @ W + b
// One thread per row; W (16 KB) + b staged in LDS; all W reads are
// wave-uniform broadcasts (no bank conflicts); acc[64] in VGPRs.
__global__ void __launch_bounds__(256) row_gemm_kernel(
    float* __restrict__ out, const float* __restrict__ W,
    const float* __restrict__ b) {
  __shared__ float Ws[D * D];
  __shared__ float bs[D];
  for (int i = threadIdx.x; i < D * D; i += 256) Ws[i] = W[i];
  if (threadIdx.x < D) bs[threadIdx.x] = b[threadIdx.x];
  __syncthreads();

  int row = blockIdx.x * blockDim.x + threadIdx.x;
  if (row >= N_NODES) return;  // no barriers after this point

  float acc[D];
#pragma unroll
  for (int j = 0; j < D; ++j) acc[j] = bs[j];

  const float4* rp = reinterpret_cast<const float4*>(out + row * D);
#pragma unroll
  for (int kc = 0; kc < 16; ++kc) {
    float4 f = rp[kc];  // all loads of this row happen before any store below
#pragma unroll
    for (int kk = 0; kk < 4; ++kk) {
      float fv = (&f.x)[kk];
      const float* wrow = &Ws[(kc * 4 + kk) * D];
#pragma unroll
      for (int j = 0; j < D; ++j) acc[j] += fv * wrow[j];
    }
  }

  float4* op = reinterpret_cast<float4*>(out + row * D);
#pragma unroll
  for (int jc = 0; jc < 16; ++jc) {
    float4 o;
    o.x = acc[jc * 4 + 0];
    o.y = acc[jc * 4 + 1];
    o.z = acc[jc * 4 + 2];
    o.w = acc[jc * 4 + 3];
    op[jc] = o;
  }
}

extern "C" void kernel_launch(void* const* d_in, const int* in_sizes, int n_in,
                              void* d_out, int out_size, void* d_ws, size_t ws_size,
                              hipStream_t stream) {
  const float* feat = (const float*)d_in[0];
  const int* src    = (const int*)d_in[1];
  const int* dst    = (const int*)d_in[2];
  const float* eps  = (const float*)d_in[3];
  const float* W    = (const float*)d_in[4];
  const float* b    = (const float*)d_in[5];
  float* out        = (float*)d_out;

  // K1: out = (1+eps)*feat   — N_NODES*D/4 float4s = 1.6M threads exactly
  init_out_kernel<<<(N_NODES * D / 4) / 256, 256, 0, stream>>>(feat, eps, out);

  // K2: edge scatter — 16 threads/edge → 25.6M threads = 100000 blocks exactly
  scatter_edges_kernel<<<(N_EDGES * 16) / 256, 256, 0, stream>>>(feat, src, dst, out);

  // K3: in-place row GEMM — one thread per row
  row_gemm_kernel<<<(N_NODES + 255) / 256, 256, 0, stream>>>(out, W, b);
}

// Round 2
// 931.442 us; speedup vs baseline: 1.5768x; 1.5768x over previous
//
#include <hip/hip_runtime.h>

#define NN 100000
#define NE 1600000
#define DD 64

constexpr int NB_SCAN = (NN + 1023) / 1024;  // 98 scan blocks

// ---------------- sort-based path ----------------

__global__ void __launch_bounds__(256) zero_kernel(int* __restrict__ p, int n) {
  int i = blockIdx.x * blockDim.x + threadIdx.x;
  if (i < n) p[i] = 0;
}

__global__ void __launch_bounds__(256) hist_kernel(const int* __restrict__ dst,
                                                   int* __restrict__ count) {
  int e = blockIdx.x * blockDim.x + threadIdx.x;  // grid exact: NE/256
  atomicAdd(&count[dst[e]], 1);
}

// per-block exclusive scan of count -> offsets, block totals -> bsums
__global__ void __launch_bounds__(1024) scan1_kernel(const int* __restrict__ count,
                                                     int* __restrict__ offsets,
                                                     int* __restrict__ bsums) {
  __shared__ int tmp[1024];
  int tid = threadIdx.x;
  int gid = blockIdx.x * 1024 + tid;
  int v = (gid < NN) ? count[gid] : 0;
  tmp[tid] = v;
  __syncthreads();
  for (int off = 1; off < 1024; off <<= 1) {
    int t = (tid >= off) ? tmp[tid - off] : 0;
    __syncthreads();
    tmp[tid] += t;
    __syncthreads();
  }
  if (gid < NN) offsets[gid] = tmp[tid] - v;          // exclusive
  if (tid == 1023) bsums[blockIdx.x] = tmp[1023];     // block total
}

// exclusive scan of the 98 block sums (single block)
__global__ void __launch_bounds__(128) scan2_kernel(int* __restrict__ bsums) {
  __shared__ int tmp[128];
  int tid = threadIdx.x;
  int v = (tid < NB_SCAN) ? bsums[tid] : 0;
  tmp[tid] = v;
  __syncthreads();
  for (int off = 1; off < 128; off <<= 1) {
    int t = (tid >= off) ? tmp[tid - off] : 0;
    __syncthreads();
    tmp[tid] += t;
    __syncthreads();
  }
  if (tid < NB_SCAN) bsums[tid] = tmp[tid] - v;       // exclusive
}

// add scanned block sums; init cursor = offsets; offsets[NN] = NE
__global__ void __launch_bounds__(256) scan3_kernel(int* __restrict__ offsets,
                                                    const int* __restrict__ bsums,
                                                    int* __restrict__ cursor) {
  int gid = blockIdx.x * blockDim.x + threadIdx.x;
  if (gid < NN) {
    int o = offsets[gid] + bsums[gid >> 10];
    offsets[gid] = o;
    cursor[gid] = o;
  } else if (gid == NN) {
    offsets[NN] = NE;
  }
}

__global__ void __launch_bounds__(256) place_kernel(const int* __restrict__ src,
                                                    const int* __restrict__ dst,
                                                    int* __restrict__ cursor,
                                                    int* __restrict__ sorted) {
  int e = blockIdx.x * blockDim.x + threadIdx.x;  // grid exact: NE/256
  int p = atomicAdd(&cursor[dst[e]], 1);
  sorted[p] = src[e];
}

// one wave per node; lane = feature dim; rst = (1+eps)*self + sum(neighbors)
__global__ void __launch_bounds__(256) pull_kernel(const float* __restrict__ feat,
                                                   const float* __restrict__ eps,
                                                   const int* __restrict__ offsets,
                                                   const int* __restrict__ sorted,
                                                   float* __restrict__ out) {
  int t = blockIdx.x * blockDim.x + threadIdx.x;  // grid exact: NN*64/256
  int node = t >> 6;
  int lane = t & 63;
  int start = offsets[node];
  int end = offsets[node + 1];
  float acc = (1.0f + eps[0]) * feat[node * DD + lane];
  int s = (start < end) ? sorted[start] : 0;  // prefetch index
  for (int k = start; k < end; ++k) {
    int sn = (k + 1 < end) ? sorted[k + 1] : 0;
    acc += feat[s * DD + lane];
    s = sn;
  }
  out[node * DD + lane] = acc;
}

// in-place tile GEMM: 128 rows/block, thread = 2 rows x 16 cols, W + rows in LDS
__global__ void __launch_bounds__(256) row_gemm2_kernel(float* __restrict__ out,
                                                        const float* __restrict__ W,
                                                        const float* __restrict__ b) {
  __shared__ float Ws[DD * DD];       // 16 KB
  __shared__ float Rs[128][DD + 1];   // 33.3 KB, +1 pad -> conflict-free column reads
  int t = threadIdx.x;
  int base = blockIdx.x * 128;

  for (int i = t; i < DD * DD / 4; i += 256)
    reinterpret_cast<float4*>(Ws)[i] = reinterpret_cast<const float4*>(W)[i];

  for (int i = t; i < 128 * 16; i += 256) {
    int r = i >> 4, c = i & 15;
    float4 v;
    if (base + r < NN)
      v = reinterpret_cast<const float4*>(out + (size_t)(base + r) * DD)[c];
    else
      v = make_float4(0.f, 0.f, 0.f, 0.f);
    Rs[r][c * 4 + 0] = v.x; Rs[r][c * 4 + 1] = v.y;
    Rs[r][c * 4 + 2] = v.z; Rs[r][c * 4 + 3] = v.w;
  }
  __syncthreads();

  int jg = t & 3;    // 16-col group
  int rq = t >> 2;   // 0..63 -> rows rq and rq+64
  float acc0[16], acc1[16];
#pragma unroll
  for (int jj = 0; jj < 16; ++jj) {
    float bv = b[jg * 16 + jj];
    acc0[jj] = bv; acc1[jj] = bv;
  }

#pragma unroll
  for (int k = 0; k < DD; ++k) {
    float f0 = Rs[rq][k];
    float f1 = Rs[rq + 64][k];
    const float4* wp = reinterpret_cast<const float4*>(&Ws[k * DD + jg * 16]);
#pragma unroll
    for (int c = 0; c < 4; ++c) {
      float4 w = wp[c];
      acc0[c * 4 + 0] += f0 * w.x; acc0[c * 4 + 1] += f0 * w.y;
      acc0[c * 4 + 2] += f0 * w.z; acc0[c * 4 + 3] += f0 * w.w;
      acc1[c * 4 + 0] += f1 * w.x; acc1[c * 4 + 1] += f1 * w.y;
      acc1[c * 4 + 2] += f1 * w.z; acc1[c * 4 + 3] += f1 * w.w;
    }
  }

  if (base + rq < NN) {
    float4* o0 = reinterpret_cast<float4*>(out + (size_t)(base + rq) * DD + jg * 16);
#pragma unroll
    for (int c = 0; c < 4; ++c)
      o0[c] = make_float4(acc0[c * 4], acc0[c * 4 + 1], acc0[c * 4 + 2], acc0[c * 4 + 3]);
  }
  if (base + rq + 64 < NN) {
    float4* o1 = reinterpret_cast<float4*>(out + (size_t)(base + rq + 64) * DD + jg * 16);
#pragma unroll
    for (int c = 0; c < 4; ++c)
      o1[c] = make_float4(acc1[c * 4], acc1[c * 4 + 1], acc1[c * 4 + 2], acc1[c * 4 + 3]);
  }
}

// ---------------- fallback path (atomic scatter), used if ws too small ----------------

__global__ void __launch_bounds__(256) init_out_kernel(const float* __restrict__ feat,
                                                       const float* __restrict__ eps,
                                                       float* __restrict__ out) {
  int i = blockIdx.x * blockDim.x + threadIdx.x;
  float e = 1.0f + eps[0];
  float4 f = reinterpret_cast<const float4*>(feat)[i];
  reinterpret_cast<float4*>(out)[i] = make_float4(e * f.x, e * f.y, e * f.z, e * f.w);
}

__global__ void __launch_bounds__(256) scatter_edges_kernel(const float* __restrict__ feat,
                                                            const int* __restrict__ src,
                                                            const int* __restrict__ dst,
                                                            float* __restrict__ out) {
  int t = blockIdx.x * blockDim.x + threadIdx.x;
  int e = t >> 4;
  int q = t & 15;
  int s = src[e];
  int d = dst[e];
  float4 v = reinterpret_cast<const float4*>(feat)[s * 16 + q];
  float* op = out + d * DD + q * 4;
  atomicAdd(op + 0, v.x);
  atomicAdd(op + 1, v.y);
  atomicAdd(op + 2, v.z);
  atomicAdd(op + 3, v.w);
}

// ---------------- launch ----------------

extern "C" void kernel_launch(void* const* d_in, const int* in_sizes, int n_in,
                              void* d_out, int out_size, void* d_ws, size_t ws_size,
                              hipStream_t stream) {
  const float* feat = (const float*)d_in[0];
  const int* src    = (const int*)d_in[1];
  const int* dst    = (const int*)d_in[2];
  const float* eps  = (const float*)d_in[3];
  const float* W    = (const float*)d_in[4];
  const float* b    = (const float*)d_in[5];
  float* out        = (float*)d_out;

  // ws layout (ints): count[NN] | offsets[NN+1 pad 8] | cursor[NN] | bsums[128] | sorted[NE]
  const size_t need_ints = (size_t)3 * NN + 136 + NE;
  if (ws_size >= need_ints * sizeof(int)) {
    int* wsI     = (int*)d_ws;
    int* count   = wsI;
    int* offsets = wsI + NN;
    int* cursor  = wsI + 2 * NN + 8;
    int* bsums   = wsI + 3 * NN + 8;
    int* sorted  = wsI + 3 * NN + 136;

    zero_kernel<<<(NN + 255) / 256, 256, 0, stream>>>(count, NN);
    hist_kernel<<<NE / 256, 256, 0, stream>>>(dst, count);
    scan1_kernel<<<NB_SCAN, 1024, 0, stream>>>(count, offsets, bsums);
    scan2_kernel<<<1, 128, 0, stream>>>(bsums);
    scan3_kernel<<<(NN + 1 + 255) / 256, 256, 0, stream>>>(offsets, bsums, cursor);
    place_kernel<<<NE / 256, 256, 0, stream>>>(src, dst, cursor, sorted);
    pull_kernel<<<(NN * 64) / 256, 256, 0, stream>>>(feat, eps, offsets, sorted, out);
    row_gemm2_kernel<<<(NN + 127) / 128, 256, 0, stream>>>(out, W, b);
  } else {
    init_out_kernel<<<(NN * DD / 4) / 256, 256, 0, stream>>>(feat, eps, out);
    scatter_edges_kernel<<<(NE * 16) / 256, 256, 0, stream>>>(feat, src, dst, out);
    row_gemm2_kernel<<<(NN + 127) / 128, 256, 0, stream>>>(out, W, b);
  }
}

// Round 3
// 448.477 us; speedup vs baseline: 3.2749x; 2.0769x over previous
//
#include <hip/hip_runtime.h>

#define NN 100000
#define NE 1600000
#define DD 64

constexpr int NB_SCAN = (NN + 1023) / 1024;  // 98 scan blocks

// ---------------- sort-based path ----------------

__global__ void __launch_bounds__(256) zero_kernel(int* __restrict__ p, int n) {
  int i = blockIdx.x * blockDim.x + threadIdx.x;
  if (i < n) p[i] = 0;
}

__global__ void __launch_bounds__(256) hist_kernel(const int* __restrict__ dst,
                                                   int* __restrict__ count) {
  int e = blockIdx.x * blockDim.x + threadIdx.x;  // grid exact: NE/256
  atomicAdd(&count[dst[e]], 1);
}

// per-block exclusive scan of count -> offsets, block totals -> bsums
__global__ void __launch_bounds__(1024) scan1_kernel(const int* __restrict__ count,
                                                     int* __restrict__ offsets,
                                                     int* __restrict__ bsums) {
  __shared__ int tmp[1024];
  int tid = threadIdx.x;
  int gid = blockIdx.x * 1024 + tid;
  int v = (gid < NN) ? count[gid] : 0;
  tmp[tid] = v;
  __syncthreads();
  for (int off = 1; off < 1024; off <<= 1) {
    int t = (tid >= off) ? tmp[tid - off] : 0;
    __syncthreads();
    tmp[tid] += t;
    __syncthreads();
  }
  if (gid < NN) offsets[gid] = tmp[tid] - v;          // exclusive
  if (tid == 1023) bsums[blockIdx.x] = tmp[1023];     // block total
}

// exclusive scan of the 98 block sums (single block)
__global__ void __launch_bounds__(128) scan2_kernel(int* __restrict__ bsums) {
  __shared__ int tmp[128];
  int tid = threadIdx.x;
  int v = (tid < NB_SCAN) ? bsums[tid] : 0;
  tmp[tid] = v;
  __syncthreads();
  for (int off = 1; off < 128; off <<= 1) {
    int t = (tid >= off) ? tmp[tid - off] : 0;
    __syncthreads();
    tmp[tid] += t;
    __syncthreads();
  }
  if (tid < NB_SCAN) bsums[tid] = tmp[tid] - v;       // exclusive
}

// add scanned block sums; init cursor = offsets; offsets[NN] = NE
__global__ void __launch_bounds__(256) scan3_kernel(int* __restrict__ offsets,
                                                    const int* __restrict__ bsums,
                                                    int* __restrict__ cursor) {
  int gid = blockIdx.x * blockDim.x + threadIdx.x;
  if (gid < NN) {
    int o = offsets[gid] + bsums[gid >> 10];
    offsets[gid] = o;
    cursor[gid] = o;
  } else if (gid == NN) {
    offsets[NN] = NE;
  }
}

__global__ void __launch_bounds__(256) place_kernel(const int* __restrict__ src,
                                                    const int* __restrict__ dst,
                                                    int* __restrict__ cursor,
                                                    int* __restrict__ sorted) {
  int e = blockIdx.x * blockDim.x + threadIdx.x;  // grid exact: NE/256
  int p = atomicAdd(&cursor[dst[e]], 1);
  sorted[p] = src[e];
}

// one wave per node; lane = feature dim; rst = (1+eps)*self + sum(neighbors)
__global__ void __launch_bounds__(256) pull_kernel(const float* __restrict__ feat,
                                                   const float* __restrict__ eps,
                                                   const int* __restrict__ offsets,
                                                   const int* __restrict__ sorted,
                                                   float* __restrict__ out) {
  int t = blockIdx.x * blockDim.x + threadIdx.x;  // grid exact: NN*64/256
  int node = t >> 6;
  int lane = t & 63;
  int start = offsets[node];
  int end = offsets[node + 1];
  float acc = (1.0f + eps[0]) * feat[node * DD + lane];
  int s = (start < end) ? sorted[start] : 0;  // prefetch index
  for (int k = start; k < end; ++k) {
    int sn = (k + 1 < end) ? sorted[k + 1] : 0;
    acc += feat[s * DD + lane];
    s = sn;
  }
  out[node * DD + lane] = acc;
}

// in-place row GEMM v3: thread = output column (lane), W column in VGPRs,
// rst broadcast via v_readlane -> v_fmac with SGPR operand. No LDS, ~90 VGPR,
// spill-proof by construction (all register arrays statically indexed).
// Wave g owns rows [16g, 16g+16); 6250 waves cover NN=100000 exactly.
__global__ void __launch_bounds__(256) row_gemm3_kernel(float* __restrict__ out,
                                                        const float* __restrict__ W,
                                                        const float* __restrict__ b) {
  int lane = threadIdx.x & 63;
  int wid  = threadIdx.x >> 6;
  int g = blockIdx.x * 4 + wid;
  if (g >= NN / 16) return;  // wave-uniform guard (6250 full waves)
  int row0 = g * 16;

  // W column `lane` into registers: w[k] = W[k][lane] (64 coalesced 256B loads, L2-hot)
  float w[64];
#pragma unroll
  for (int k = 0; k < 64; ++k) w[k] = W[k * DD + lane];
  float bv = b[lane];

#pragma unroll
  for (int batch = 0; batch < 2; ++batch) {
    int rbase = row0 + batch * 8;
    float rst[8], acc[8];
#pragma unroll
    for (int r = 0; r < 8; ++r) rst[r] = out[(size_t)(rbase + r) * DD + lane];
#pragma unroll
    for (int r = 0; r < 8; ++r) acc[r] = bv;
#pragma unroll
    for (int k = 0; k < 64; ++k) {
#pragma unroll
      for (int r = 0; r < 8; ++r) {
        float s = __uint_as_float(__builtin_amdgcn_readlane(__float_as_uint(rst[r]), k));
        acc[r] = fmaf(s, w[k], acc[r]);
      }
    }
    // all loads of this batch's rows happened above; wave owns these rows exclusively
#pragma unroll
    for (int r = 0; r < 8; ++r) out[(size_t)(rbase + r) * DD + lane] = acc[r];
  }
}

// ---------------- fallback path (atomic scatter), used if ws too small ----------------

__global__ void __launch_bounds__(256) init_out_kernel(const float* __restrict__ feat,
                                                       const float* __restrict__ eps,
                                                       float* __restrict__ out) {
  int i = blockIdx.x * blockDim.x + threadIdx.x;
  float e = 1.0f + eps[0];
  float4 f = reinterpret_cast<const float4*>(feat)[i];
  reinterpret_cast<float4*>(out)[i] = make_float4(e * f.x, e * f.y, e * f.z, e * f.w);
}

__global__ void __launch_bounds__(256) scatter_edges_kernel(const float* __restrict__ feat,
                                                            const int* __restrict__ src,
                                                            const int* __restrict__ dst,
                                                            float* __restrict__ out) {
  int t = blockIdx.x * blockDim.x + threadIdx.x;
  int e = t >> 4;
  int q = t & 15;
  int s = src[e];
  int d = dst[e];
  float4 v = reinterpret_cast<const float4*>(feat)[s * 16 + q];
  float* op = out + d * DD + q * 4;
  atomicAdd(op + 0, v.x);
  atomicAdd(op + 1, v.y);
  atomicAdd(op + 2, v.z);
  atomicAdd(op + 3, v.w);
}

// ---------------- launch ----------------

extern "C" void kernel_launch(void* const* d_in, const int* in_sizes, int n_in,
                              void* d_out, int out_size, void* d_ws, size_t ws_size,
                              hipStream_t stream) {
  const float* feat = (const float*)d_in[0];
  const int* src    = (const int*)d_in[1];
  const int* dst    = (const int*)d_in[2];
  const float* eps  = (const float*)d_in[3];
  const float* W    = (const float*)d_in[4];
  const float* b    = (const float*)d_in[5];
  float* out        = (float*)d_out;

  const int gemm_grid = (NN / 16 + 3) / 4;  // 6250 waves / 4 per block = 1563 blocks

  // ws layout (ints): count[NN] | offsets[NN+1 pad 8] | cursor[NN] | bsums[128] | sorted[NE]
  const size_t need_ints = (size_t)3 * NN + 136 + NE;
  if (ws_size >= need_ints * sizeof(int)) {
    int* wsI     = (int*)d_ws;
    int* count   = wsI;
    int* offsets = wsI + NN;
    int* cursor  = wsI + 2 * NN + 8;
    int* bsums   = wsI + 3 * NN + 8;
    int* sorted  = wsI + 3 * NN + 136;

    zero_kernel<<<(NN + 255) / 256, 256, 0, stream>>>(count, NN);
    hist_kernel<<<NE / 256, 256, 0, stream>>>(dst, count);
    scan1_kernel<<<NB_SCAN, 1024, 0, stream>>>(count, offsets, bsums);
    scan2_kernel<<<1, 128, 0, stream>>>(bsums);
    scan3_kernel<<<(NN + 1 + 255) / 256, 256, 0, stream>>>(offsets, bsums, cursor);
    place_kernel<<<NE / 256, 256, 0, stream>>>(src, dst, cursor, sorted);
    pull_kernel<<<(NN * 64) / 256, 256, 0, stream>>>(feat, eps, offsets, sorted, out);
    row_gemm3_kernel<<<gemm_grid, 256, 0, stream>>>(out, W, b);
  } else {
    init_out_kernel<<<(NN * DD / 4) / 256, 256, 0, stream>>>(feat, eps, out);
    scatter_edges_kernel<<<(NE * 16) / 256, 256, 0, stream>>>(feat, src, dst, out);
    row_gemm3_kernel<<<gemm_grid, 256, 0, stream>>>(out, W, b);
  }
}

// Round 4
// 359.808 us; speedup vs baseline: 4.0820x; 1.2464x over previous
//
#include <hip/hip_runtime.h>

#define NN 100000
#define NE 1600000
#define DD 64

constexpr int NB_SCAN = (NN + 1023) / 1024;  // 98 scan blocks

// ---------------- sort-based path ----------------

__global__ void __launch_bounds__(256) zero_kernel(int* __restrict__ p, int n) {
  int i = blockIdx.x * blockDim.x + threadIdx.x;
  if (i < n) p[i] = 0;
}

__global__ void __launch_bounds__(256) hist_kernel(const int* __restrict__ dst,
                                                   int* __restrict__ count) {
  int e = blockIdx.x * blockDim.x + threadIdx.x;  // grid exact: NE/256
  atomicAdd(&count[dst[e]], 1);
}

// per-block exclusive scan of count -> offsets, block totals -> bsums
__global__ void __launch_bounds__(1024) scan1_kernel(const int* __restrict__ count,
                                                     int* __restrict__ offsets,
                                                     int* __restrict__ bsums) {
  __shared__ int tmp[1024];
  int tid = threadIdx.x;
  int gid = blockIdx.x * 1024 + tid;
  int v = (gid < NN) ? count[gid] : 0;
  tmp[tid] = v;
  __syncthreads();
  for (int off = 1; off < 1024; off <<= 1) {
    int t = (tid >= off) ? tmp[tid - off] : 0;
    __syncthreads();
    tmp[tid] += t;
    __syncthreads();
  }
  if (gid < NN) offsets[gid] = tmp[tid] - v;          // exclusive
  if (tid == 1023) bsums[blockIdx.x] = tmp[1023];     // block total
}

// exclusive scan of the 98 block sums (single block)
__global__ void __launch_bounds__(128) scan2_kernel(int* __restrict__ bsums) {
  __shared__ int tmp[128];
  int tid = threadIdx.x;
  int v = (tid < NB_SCAN) ? bsums[tid] : 0;
  tmp[tid] = v;
  __syncthreads();
  for (int off = 1; off < 128; off <<= 1) {
    int t = (tid >= off) ? tmp[tid - off] : 0;
    __syncthreads();
    tmp[tid] += t;
    __syncthreads();
  }
  if (tid < NB_SCAN) bsums[tid] = tmp[tid] - v;       // exclusive
}

// add scanned block sums; init cursor = offsets; offsets[NN] = NE
__global__ void __launch_bounds__(256) scan3_kernel(int* __restrict__ offsets,
                                                    const int* __restrict__ bsums,
                                                    int* __restrict__ cursor) {
  int gid = blockIdx.x * blockDim.x + threadIdx.x;
  if (gid < NN) {
    int o = offsets[gid] + bsums[gid >> 10];
    offsets[gid] = o;
    cursor[gid] = o;
  } else if (gid == NN) {
    offsets[NN] = NE;
  }
}

__global__ void __launch_bounds__(256) place_kernel(const int* __restrict__ src,
                                                    const int* __restrict__ dst,
                                                    int* __restrict__ cursor,
                                                    int* __restrict__ sorted) {
  int e = blockIdx.x * blockDim.x + threadIdx.x;  // grid exact: NE/256
  int p = atomicAdd(&cursor[dst[e]], 1);
  sorted[p] = src[e];
}

// pull v4: 16 lanes (quarter-wave) per node, lane owns one float4 quad of the
// 64-dim row. Neighbor loop unrolled x4 -> 4 row-gathers in flight per node,
// 16 per wave (vs 1 in v3's wave-per-node serial loop). Lane-local float4
// accumulate, no cross-lane reduce. Fuses the (1+eps)*self term.
__global__ void __launch_bounds__(256) pull4_kernel(const float* __restrict__ feat,
                                                    const float* __restrict__ eps,
                                                    const int* __restrict__ offsets,
                                                    const int* __restrict__ sorted,
                                                    float* __restrict__ out) {
  int t = blockIdx.x * blockDim.x + threadIdx.x;  // grid exact: NN*16/256 = 6250
  int node = t >> 4;
  int q = t & 15;
  const float4* f4 = reinterpret_cast<const float4*>(feat);

  int start = offsets[node];
  int end   = offsets[node + 1];
  float e = 1.0f + eps[0];
  float4 self = f4[(size_t)node * 16 + q];
  float ax = e * self.x, ay = e * self.y, az = e * self.z, aw = e * self.w;

  int k = start;
  for (; k + 4 <= end; k += 4) {
    int s0 = sorted[k + 0];
    int s1 = sorted[k + 1];
    int s2 = sorted[k + 2];
    int s3 = sorted[k + 3];
    float4 v0 = f4[(size_t)s0 * 16 + q];
    float4 v1 = f4[(size_t)s1 * 16 + q];
    float4 v2 = f4[(size_t)s2 * 16 + q];
    float4 v3 = f4[(size_t)s3 * 16 + q];
    ax += (v0.x + v1.x) + (v2.x + v3.x);
    ay += (v0.y + v1.y) + (v2.y + v3.y);
    az += (v0.z + v1.z) + (v2.z + v3.z);
    aw += (v0.w + v1.w) + (v2.w + v3.w);
  }
  for (; k < end; ++k) {
    int s = sorted[k];
    float4 v = f4[(size_t)s * 16 + q];
    ax += v.x; ay += v.y; az += v.z; aw += v.w;
  }

  reinterpret_cast<float4*>(out)[(size_t)node * 16 + q] =
      make_float4(ax, ay, az, aw);
}

// in-place row GEMM v3: thread = output column (lane), W column in VGPRs,
// rst broadcast via v_readlane -> v_fmac with SGPR operand. No LDS, ~90 VGPR,
// spill-proof by construction (all register arrays statically indexed).
__global__ void __launch_bounds__(256) row_gemm3_kernel(float* __restrict__ out,
                                                        const float* __restrict__ W,
                                                        const float* __restrict__ b) {
  int lane = threadIdx.x & 63;
  int wid  = threadIdx.x >> 6;
  int g = blockIdx.x * 4 + wid;
  if (g >= NN / 16) return;  // wave-uniform guard (6250 full waves)
  int row0 = g * 16;

  float w[64];
#pragma unroll
  for (int k = 0; k < 64; ++k) w[k] = W[k * DD + lane];
  float bv = b[lane];

#pragma unroll
  for (int batch = 0; batch < 2; ++batch) {
    int rbase = row0 + batch * 8;
    float rst[8], acc[8];
#pragma unroll
    for (int r = 0; r < 8; ++r) rst[r] = out[(size_t)(rbase + r) * DD + lane];
#pragma unroll
    for (int r = 0; r < 8; ++r) acc[r] = bv;
#pragma unroll
    for (int k = 0; k < 64; ++k) {
#pragma unroll
      for (int r = 0; r < 8; ++r) {
        float s = __uint_as_float(__builtin_amdgcn_readlane(__float_as_uint(rst[r]), k));
        acc[r] = fmaf(s, w[k], acc[r]);
      }
    }
#pragma unroll
    for (int r = 0; r < 8; ++r) out[(size_t)(rbase + r) * DD + lane] = acc[r];
  }
}

// ---------------- fallback path (atomic scatter), used if ws too small ----------------

__global__ void __launch_bounds__(256) init_out_kernel(const float* __restrict__ feat,
                                                       const float* __restrict__ eps,
                                                       float* __restrict__ out) {
  int i = blockIdx.x * blockDim.x + threadIdx.x;
  float e = 1.0f + eps[0];
  float4 f = reinterpret_cast<const float4*>(feat)[i];
  reinterpret_cast<float4*>(out)[i] = make_float4(e * f.x, e * f.y, e * f.z, e * f.w);
}

__global__ void __launch_bounds__(256) scatter_edges_kernel(const float* __restrict__ feat,
                                                            const int* __restrict__ src,
                                                            const int* __restrict__ dst,
                                                            float* __restrict__ out) {
  int t = blockIdx.x * blockDim.x + threadIdx.x;
  int e = t >> 4;
  int q = t & 15;
  int s = src[e];
  int d = dst[e];
  float4 v = reinterpret_cast<const float4*>(feat)[s * 16 + q];
  float* op = out + d * DD + q * 4;
  atomicAdd(op + 0, v.x);
  atomicAdd(op + 1, v.y);
  atomicAdd(op + 2, v.z);
  atomicAdd(op + 3, v.w);
}

// ---------------- launch ----------------

extern "C" void kernel_launch(void* const* d_in, const int* in_sizes, int n_in,
                              void* d_out, int out_size, void* d_ws, size_t ws_size,
                              hipStream_t stream) {
  const float* feat = (const float*)d_in[0];
  const int* src    = (const int*)d_in[1];
  const int* dst    = (const int*)d_in[2];
  const float* eps  = (const float*)d_in[3];
  const float* W    = (const float*)d_in[4];
  const float* b    = (const float*)d_in[5];
  float* out        = (float*)d_out;

  const int gemm_grid = (NN / 16 + 3) / 4;  // 6250 waves / 4 per block

  // ws layout (ints): count[NN] | offsets[NN+1 pad 8] | cursor[NN] | bsums[128] | sorted[NE]
  const size_t need_ints = (size_t)3 * NN + 136 + NE;
  if (ws_size >= need_ints * sizeof(int)) {
    int* wsI     = (int*)d_ws;
    int* count   = wsI;
    int* offsets = wsI + NN;
    int* cursor  = wsI + 2 * NN + 8;
    int* bsums   = wsI + 3 * NN + 8;
    int* sorted  = wsI + 3 * NN + 136;

    zero_kernel<<<(NN + 255) / 256, 256, 0, stream>>>(count, NN);
    hist_kernel<<<NE / 256, 256, 0, stream>>>(dst, count);
    scan1_kernel<<<NB_SCAN, 1024, 0, stream>>>(count, offsets, bsums);
    scan2_kernel<<<1, 128, 0, stream>>>(bsums);
    scan3_kernel<<<(NN + 1 + 255) / 256, 256, 0, stream>>>(offsets, bsums, cursor);
    place_kernel<<<NE / 256, 256, 0, stream>>>(src, dst, cursor, sorted);
    pull4_kernel<<<(NN * 16) / 256, 256, 0, stream>>>(feat, eps, offsets, sorted, out);
    row_gemm3_kernel<<<gemm_grid, 256, 0, stream>>>(out, W, b);
  } else {
    init_out_kernel<<<(NN * DD / 4) / 256, 256, 0, stream>>>(feat, eps, out);
    scatter_edges_kernel<<<(NE * 16) / 256, 256, 0, stream>>>(feat, src, dst, out);
    row_gemm3_kernel<<<gemm_grid, 256, 0, stream>>>(out, W, b);
  }
}